// Round 2
// baseline (7040.571 us; speedup 1.0000x reference)
//
#include <hip/hip_runtime.h>
#include <hip/hip_bf16.h>
#include <stdint.h>

#define NUM_CLASSES 109

__device__ __forceinline__ float bf2f(uint32_t u) {
    union { uint32_t i; float f; } v; v.i = u << 16; return v.f;
}

// ---------------- dtype detection: are float tensors f32 or bf16? ----------------
// Interpret low u16 of first 4096 words of x as bf16. True bf16 data (x~N(0,1))
// always decodes |v| < 1e4; f32 mantissa halves decode huge/NaN ~45% of the time.
__global__ __launch_bounds__(256) void detect_kernel(const uint32_t* __restrict__ xw,
                                                     int* __restrict__ flag) {
    __shared__ int cnt[256];
    int c = 0;
    for (int i = threadIdx.x; i < 4096; i += 256) {
        float a = bf2f(xw[i] & 0xffffu);
        if (!(fabsf(a) < 1e4f)) c++;   // counts NaN/Inf/huge
    }
    cnt[threadIdx.x] = c;
    __syncthreads();
    for (int s = 128; s > 0; s >>= 1) {
        if (threadIdx.x < s) cnt[threadIdx.x] += cnt[threadIdx.x + s];
        __syncthreads();
    }
    if (threadIdx.x == 0) flag[0] = (cnt[0] > 256) ? 1 : 0;  // 1 => f32 tensors
}

// ---------------- degree: atomic count of incoming edges ----------------
__global__ __launch_bounds__(256) void deg_kernel(const int* __restrict__ dst,
                                                  float* __restrict__ deg, int E) {
    int e = blockIdx.x * 256 + threadIdx.x;
    if (e < E) atomicAdd(&deg[dst[e]], 1.0f);
}

// ---------------- h = x @ W  ([N,64] x [64,32] -> bf16 [N,32]) ----------------
template <bool F32>
__device__ __forceinline__ void h_body(const void* __restrict__ xv,
                                       const void* __restrict__ Wv,
                                       __hip_bfloat16* __restrict__ h, int N) {
    __shared__ float xs[64][64];
    const int j = threadIdx.x & 31;     // output channel
    const int nslot = threadIdx.x >> 5;

    float w[64];
#pragma unroll
    for (int k = 0; k < 64; k++) {
        if (F32) w[k] = ((const float*)Wv)[k * 32 + j];
        else     w[k] = bf2f((uint32_t)((const ushort*)Wv)[k * 32 + j]);
    }

    int ntiles = (N + 63) >> 6;
    for (int tile = blockIdx.x; tile < ntiles; tile += gridDim.x) {
        int n0 = tile << 6;
        __syncthreads();
        if (F32) {
            // 64 rows x 16 float4
            for (int idx = threadIdx.x; idx < 1024; idx += 256) {
                int row = idx >> 4, q = idx & 15;
                int n = n0 + row;
                float4 f = make_float4(0.f, 0.f, 0.f, 0.f);
                if (n < N) f = ((const float4*)xv)[(size_t)n * 16 + q];
                float* d = &xs[row][q << 2];
                d[0] = f.x; d[1] = f.y; d[2] = f.z; d[3] = f.w;
            }
        } else {
            // 64 rows x 8 uint4 (8 bf16 each)
            for (int idx = threadIdx.x; idx < 512; idx += 256) {
                int row = idx >> 3, c0 = (idx & 7) << 3;
                int n = n0 + row;
                uint4 pk = make_uint4(0, 0, 0, 0);
                if (n < N) pk = *(const uint4*)((const ushort*)xv + (size_t)n * 64 + c0);
                float* d = &xs[row][c0];
                d[0] = bf2f(pk.x & 0xffff); d[1] = bf2f(pk.x >> 16);
                d[2] = bf2f(pk.y & 0xffff); d[3] = bf2f(pk.y >> 16);
                d[4] = bf2f(pk.z & 0xffff); d[5] = bf2f(pk.z >> 16);
                d[6] = bf2f(pk.w & 0xffff); d[7] = bf2f(pk.w >> 16);
            }
        }
        __syncthreads();
        for (int r = nslot; r < 64; r += 8) {
            int n = n0 + r;
            if (n >= N) break;
            float acc = 0.f;
#pragma unroll
            for (int k = 0; k < 64; k++) acc += xs[r][k] * w[k];
            h[(size_t)n * 32 + j] = __float2bfloat16(acc);
        }
    }
}

__global__ __launch_bounds__(256) void h_kernel(const void* x, const void* W,
                                                __hip_bfloat16* h, int N,
                                                const int* __restrict__ flag) {
    if (*flag) h_body<true>(x, W, h, N);
    else       h_body<false>(x, W, h, N);
}

// ---------------- edge scatter: agg[dst-n0] += h[src] * norm, dst in [n0,n1) ----------------
__global__ __launch_bounds__(256) void scatter_kernel(const int* __restrict__ src,
                                                      const int* __restrict__ dst,
                                                      const float* __restrict__ deg,
                                                      const __hip_bfloat16* __restrict__ h,
                                                      float* __restrict__ agg, int E,
                                                      int n0, int n1) {
    const int ch = threadIdx.x & 31;
    const int elane = threadIdx.x >> 5;          // 0..7
    const int e0 = blockIdx.x * 256;
    const ushort* hu = (const ushort*)h;
#pragma unroll 4
    for (int i = 0; i < 32; i++) {
        int e = e0 + i * 8 + elane;
        if (e < E) {
            int d = dst[e];
            if (d >= n0 && d < n1) {
                int s = src[e];
                float norm = rsqrtf((deg[s] + 1.0f) * (deg[d] + 1.0f));
                float hv = bf2f((uint32_t)hu[(size_t)s * 32 + ch]);
                atomicAdd(&agg[(size_t)(d - n0) * 32 + ch], hv * norm);
            }
        }
    }
}

// ---------------- finalize node (self-loop + bias + tanh), accumulate per-graph ----------------
template <bool F32>
__device__ __forceinline__ void pool_body(const float* __restrict__ agg,
                                          const __hip_bfloat16* __restrict__ h,
                                          const float* __restrict__ deg,
                                          const void* __restrict__ bgcn,
                                          const int* __restrict__ batch,
                                          float* __restrict__ embacc,
                                          float* __restrict__ cntS,
                                          int side, int n0, int n1) {
    const int ch = threadIdx.x & 31;
    const int n = n0 + blockIdx.x * 8 + (threadIdx.x >> 5);
    if (n >= n1) return;
    float bias;
    if (F32) bias = ((const float*)bgcn)[ch];
    else     bias = bf2f((uint32_t)((const ushort*)bgcn)[ch]);
    const float d = deg[n] + 1.0f;
    float v = agg[(size_t)(n - n0) * 32 + ch]
            + bf2f((uint32_t)((const ushort*)h)[(size_t)n * 32 + ch]) * (1.0f / d)
            + bias;
    int g = batch[n];
    atomicAdd(&embacc[(size_t)g * 64 + side * 32 + ch], tanhf(v));
    if (ch == 0) atomicAdd(&cntS[g], 1.0f);
}

__global__ __launch_bounds__(256) void pool_kernel(const float* agg, const __hip_bfloat16* h,
                                                   const float* deg, const void* bgcn,
                                                   const int* batch, float* embacc,
                                                   float* cntS, int side, int n0, int n1,
                                                   const int* __restrict__ flag) {
    if (*flag) pool_body<true>(agg, h, deg, bgcn, batch, embacc, cntS, side, n0, n1);
    else       pool_body<false>(agg, h, deg, bgcn, batch, embacc, cntS, side, n0, n1);
}

// ---------------- out = tanh(embacc/cnt) @ W_out + b_out ----------------
template <bool F32>
__device__ __forceinline__ void out_body(const float* __restrict__ embacc,
                                         const float* __restrict__ cnt,
                                         const void* __restrict__ Wo,
                                         const void* __restrict__ bo,
                                         void* __restrict__ out, int G) {
    __shared__ float lw[64 * NUM_CLASSES];
    __shared__ float le[32 * 64];
    __shared__ float lb[NUM_CLASSES];
    const int g0 = blockIdx.x * 32;
    for (int i = threadIdx.x; i < 64 * NUM_CLASSES; i += 256) {
        if (F32) lw[i] = ((const float*)Wo)[i];
        else     lw[i] = bf2f((uint32_t)((const ushort*)Wo)[i]);
    }
    for (int i = threadIdx.x; i < NUM_CLASSES; i += 256) {
        if (F32) lb[i] = ((const float*)bo)[i];
        else     lb[i] = bf2f((uint32_t)((const ushort*)bo)[i]);
    }
    for (int i = threadIdx.x; i < 32 * 64; i += 256) {
        int g = g0 + (i >> 6), k = i & 63;
        float v = 0.f;
        if (g < G) {
            float c = cnt[(size_t)(k >> 5) * G + g];
            v = tanhf(embacc[(size_t)g * 64 + k] / fmaxf(c, 1.0f));
        }
        le[i] = v;
    }
    __syncthreads();
    for (int o = threadIdx.x; o < 32 * NUM_CLASSES; o += 256) {
        int gl = o / NUM_CLASSES, c = o - gl * NUM_CLASSES;
        int g = g0 + gl;
        if (g >= G) continue;
        float acc = lb[c];
#pragma unroll 16
        for (int k = 0; k < 64; k++) acc += le[gl * 64 + k] * lw[k * NUM_CLASSES + c];
        if (F32) ((float*)out)[(size_t)g * NUM_CLASSES + c] = acc;
        else     ((__hip_bfloat16*)out)[(size_t)g * NUM_CLASSES + c] = __float2bfloat16(acc);
    }
}

__global__ __launch_bounds__(256) void out_kernel(const float* embacc, const float* cnt,
                                                  const void* Wo, const void* bo,
                                                  void* out, int G,
                                                  const int* __restrict__ flag) {
    if (*flag) out_body<true>(embacc, cnt, Wo, bo, out, G);
    else       out_body<false>(embacc, cnt, Wo, bo, out, G);
}

extern "C" void kernel_launch(void* const* d_in, const int* in_sizes, int n_in,
                              void* d_out, int out_size, void* d_ws, size_t ws_size,
                              hipStream_t stream) {
    const int N = in_sizes[0] / 64;          // nodes
    const int E = in_sizes[1] / 2;           // edges
    const int G = out_size / NUM_CLASSES;    // graphs

    // workspace layout (all offsets multiples of 256 B for N,G here)
    char* ws = (char*)d_ws;
    size_t o = 0;
    __hip_bfloat16* h = (__hip_bfloat16*)(ws + o); o += (size_t)N * 64;       // N*32 bf16
    float* deg    = (float*)(ws + o);              o += (size_t)N * 4;        // N f32
    float* embacc = (float*)(ws + o);              o += (size_t)G * 64 * 4;   // G*64 f32
    float* cnt    = (float*)(ws + o);              o += (size_t)G * 2 * 4;    // 2*G f32
    int* flag     = (int*)(ws + o);                o += 256;
    float* agg    = (float*)(ws + o);                                          // NC*32 f32

    size_t rem = (ws_size > o) ? (ws_size - o) : 0;
    long long NC = (long long)(rem / 128);   // f32*32 per node
    if (NC > N) NC = N;
    NC &= ~255LL;
    if (NC < 256) NC = 256;                  // last resort; ws assumed at least this big
    const int nchunk = (int)(((long long)N + NC - 1) / NC);

    detect_kernel<<<1, 256, 0, stream>>>((const uint32_t*)d_in[0], flag);
    hipMemsetAsync(embacc, 0, (size_t)G * 64 * 4, stream);
    hipMemsetAsync(cnt, 0, (size_t)G * 8, stream);

    for (int side = 0; side < 2; side++) {
        const void* x   = d_in[side * 3 + 0];
        const int* ei   = (const int*)d_in[side * 3 + 1];
        const int* batch = (const int*)d_in[side * 3 + 2];

        hipMemsetAsync(deg, 0, (size_t)N * 4, stream);
        deg_kernel<<<(E + 255) / 256, 256, 0, stream>>>(ei + E, deg, E);
        h_kernel<<<2048, 256, 0, stream>>>(x, d_in[7], h, N, flag);

        for (int c = 0; c < nchunk; c++) {
            int n0 = (int)((long long)c * NC);
            int n1 = (int)((long long)(c + 1) * NC < N ? (long long)(c + 1) * NC : N);
            hipMemsetAsync(agg, 0, (size_t)(n1 - n0) * 128, stream);
            scatter_kernel<<<(E + 255) / 256, 256, 0, stream>>>(ei, ei + E, deg, h, agg, E, n0, n1);
            pool_kernel<<<((n1 - n0) + 7) / 8, 256, 0, stream>>>(agg, h, deg, d_in[8], batch,
                                                                 embacc, cnt + (size_t)side * G,
                                                                 side, n0, n1, flag);
        }
    }
    out_kernel<<<(G + 31) / 32, 256, 0, stream>>>(embacc, cnt, d_in[9], d_in[10], d_out, G, flag);
}